// Round 2
// baseline (160.255 us; speedup 1.0000x reference)
//
#include <hip/hip_runtime.h>

// SSIM, fused separable, column-sliding register-window design.
// Each block: 256 threads, strip of 256 cols x 64 rows. Each thread owns one
// column; 5-quantity x 12-deep register ring holds H-pass results; V-pass is
// pure register FMAs. Input rows staged through a 2-row LDS ring.

#define IMG_H 512
#define IMG_W 512
#define N_PLANES 48
#define KW 11
#define HALO 5
#define STRIP_W 256
#define STRIP_H 64
#define BLOCK 256
#define PITCH 268                         // 266 used + 2 pad for b128 span
#define STRIPS_X (IMG_W / STRIP_W)        // 2
#define STRIPS_Y (IMG_H / STRIP_H)        // 8
#define NBLK (N_PLANES * STRIPS_X * STRIPS_Y)  // 768
#define C1_CONST 1.0e-4f
#define C2_CONST 9.0e-4f

__device__ __forceinline__ float bcastf(float x) {
  return __uint_as_float(__builtin_amdgcn_readfirstlane(__float_as_uint(x)));
}

#define LOADROW(RN) { \
    v1c = 0.f; v2c = 0.f; v1t = 0.f; v2t = 0.f; \
    const int rn_ = (RN); \
    if (rn_ >= 0 && rn_ < IMG_H) { \
      const float* __restrict__ r1_ = p1 + (size_t)rn_ * IMG_W; \
      const float* __restrict__ r2_ = p2 + (size_t)rn_ * IMG_W; \
      if (gx >= 0 && gx < IMG_W) { v1c = r1_[gx]; v2c = r2_[gx]; } \
      if (tail && gx2 < IMG_W)   { v1t = r1_[gx2]; v2t = r2_[gx2]; } \
    } \
  }

#define TAP(J, AV, BV) { const float wj_ = W[(J)]; \
    const float t1_ = wj_ * (AV); const float t2_ = wj_ * (BV); \
    m1_ += t1_; m2_ += t2_; \
    q11_ += t1_ * (AV); q22_ += t2_ * (BV); q12_ += t1_ * (BV); }

#define STEP(P, EMIT) { \
  { float* d1_ = s1[(P) & 1]; float* d2_ = s2[(P) & 1]; \
    d1_[tid] = v1c; d2_[tid] = v2c; \
    if (tail) { d1_[tid + BLOCK] = v1t; d2_[tid + BLOCK] = v2t; } } \
  LOADROW(gr + 1) \
  __syncthreads(); \
  { const float4* sp1_ = (const float4*)&s1[(P) & 1][base4]; \
    const float4* sp2_ = (const float4*)&s2[(P) & 1][base4]; \
    const float4 A0 = sp1_[0], A1 = sp1_[1], A2 = sp1_[2], A3 = sp1_[3]; \
    const float4 B0 = sp2_[0], B1 = sp2_[1], B2 = sp2_[2], B3 = sp2_[3]; \
    float m1_ = 0.f, m2_ = 0.f, q11_ = 0.f, q22_ = 0.f, q12_ = 0.f; \
    TAP(0, A0.x, B0.x) TAP(1, A0.y, B0.y) TAP(2, A0.z, B0.z) TAP(3, A0.w, B0.w) \
    TAP(4, A1.x, B1.x) TAP(5, A1.y, B1.y) TAP(6, A1.z, B1.z) TAP(7, A1.w, B1.w) \
    TAP(8, A2.x, B2.x) TAP(9, A2.y, B2.y) TAP(10, A2.z, B2.z) TAP(11, A2.w, B2.w) \
    TAP(12, A3.x, B3.x) TAP(13, A3.y, B3.y) \
    win[0][(P)] = m1_; win[1][(P)] = m2_; \
    win[2][(P)] = q11_; win[3][(P)] = q22_; win[4][(P)] = q12_; } \
  if (EMIT) { \
    float vm1_ = 0.f, vm2_ = 0.f, w11_ = 0.f, w22_ = 0.f, w12_ = 0.f; \
    _Pragma("unroll") \
    for (int k_ = 0; k_ < KW; ++k_) { \
      const int q_ = ((P) + 2 + k_) % 12; const float w_ = wk[k_]; \
      vm1_ += w_ * win[0][q_]; vm2_ += w_ * win[1][q_]; \
      w11_ += w_ * win[2][q_]; w22_ += w_ * win[3][q_]; \
      w12_ += w_ * win[4][q_]; } \
    const float mu11_ = vm1_ * vm1_, mu22_ = vm2_ * vm2_, mu12_ = vm1_ * vm2_; \
    const float sg1_ = w11_ - mu11_, sg2_ = w22_ - mu22_, sg12_ = w12_ - mu12_; \
    const float num_ = (2.f * mu12_ + C1_CONST) * (2.f * sg12_ + C2_CONST); \
    const float den_ = (mu11_ + mu22_ + C1_CONST) * (sg1_ + sg2_ + C2_CONST); \
    acc += num_ / den_; } \
  gr++; \
}

__global__ __launch_bounds__(BLOCK) void ssim_strip_kernel(
    const float* __restrict__ img1,
    const float* __restrict__ img2,
    const float* __restrict__ kern2d,
    float* __restrict__ partial)
{
  __shared__ float s1[2][PITCH];
  __shared__ float s2[2][PITCH];
  __shared__ float wk_lds[KW];
  __shared__ float wave_sums[BLOCK / 64];

  const int tid = threadIdx.x;

  // 1D kernel = row sums of normalized 2D kernel (exactly the normalized 1D Gaussian).
  if (tid < KW) {
    float s = 0.f;
    #pragma unroll
    for (int j = 0; j < KW; ++j) s += kern2d[tid * KW + j];
    wk_lds[tid] = s;
  }
  __syncthreads();

  float wk[KW];
  #pragma unroll
  for (int k = 0; k < KW; ++k) wk[k] = bcastf(wk_lds[k]);

  // Per-thread zero-padded H-pass weights: window regs are [ph, ph+10] of the
  // 14-float span starting at tid&~3; W[j] = w[j-ph], 0 outside.
  const int ph = tid & 3;
  float W[14];
  #pragma unroll
  for (int j = 0; j < 14; ++j) {
    const int idx = j - ph;
    const int cidx = idx < 0 ? 0 : (idx > 10 ? 10 : idx);
    W[j] = (idx == cidx) ? wk_lds[cidx] : 0.f;
  }

  const int bid   = blockIdx.x;
  const int plane = bid / (STRIPS_X * STRIPS_Y);
  const int srem  = bid % (STRIPS_X * STRIPS_Y);
  const int y0    = (srem / STRIPS_X) * STRIP_H;
  const int x0    = (srem % STRIPS_X) * STRIP_W;
  const float* __restrict__ p1 = img1 + (size_t)plane * IMG_H * IMG_W;
  const float* __restrict__ p2 = img2 + (size_t)plane * IMG_H * IMG_W;

  const int  gx    = x0 - HALO + tid;      // global col of staged idx tid
  const int  gx2   = gx + BLOCK;
  const bool tail  = (tid < (PITCH - BLOCK));
  const int  base4 = tid & ~3;

  float win[5][12];
  float v1c, v2c, v1t, v2t;
  float acc = 0.f;
  int gr = y0 - HALO;

  LOADROW(gr)   // prologue: row y0-5 into regs

  // 74 steps total: 10 warmup (H only), 64 emitting. Phase = step mod 12,
  // LDS buffer = phase & 1 (12 even -> parity consistent across the loop).
  STEP(0, 0) STEP(1, 0) STEP(2, 0) STEP(3, 0) STEP(4, 0)
  STEP(5, 0) STEP(6, 0) STEP(7, 0) STEP(8, 0) STEP(9, 0)
  STEP(10, 1) STEP(11, 1)
  #pragma unroll 1
  for (int it = 0; it < 5; ++it) {
    STEP(0, 1) STEP(1, 1) STEP(2, 1) STEP(3, 1) STEP(4, 1) STEP(5, 1)
    STEP(6, 1) STEP(7, 1) STEP(8, 1) STEP(9, 1) STEP(10, 1) STEP(11, 1)
  }
  STEP(0, 1) STEP(1, 1)

  // Block reduction.
  #pragma unroll
  for (int off = 32; off > 0; off >>= 1)
    acc += __shfl_down(acc, off, 64);
  if ((tid & 63) == 0) wave_sums[tid >> 6] = acc;
  __syncthreads();
  if (tid == 0)
    partial[bid] = wave_sums[0] + wave_sums[1] + wave_sums[2] + wave_sums[3];
}

__global__ __launch_bounds__(256) void ssim_reduce_kernel(
    const float* __restrict__ partial, float* __restrict__ out)
{
  const int tid = threadIdx.x;
  double acc = 0.0;
  for (int i = tid; i < NBLK; i += 256) acc += (double)partial[i];
  #pragma unroll
  for (int off = 32; off > 0; off >>= 1)
    acc += __shfl_down(acc, off, 64);
  __shared__ double wsums[4];
  if ((tid & 63) == 0) wsums[tid >> 6] = acc;
  __syncthreads();
  if (tid == 0) {
    const double total = wsums[0] + wsums[1] + wsums[2] + wsums[3];
    const double inv_n = 1.0 / ((double)N_PLANES * IMG_H * IMG_W);
    out[0] = (float)(total * inv_n);
  }
}

extern "C" void kernel_launch(void* const* d_in, const int* in_sizes, int n_in,
                              void* d_out, int out_size, void* d_ws, size_t ws_size,
                              hipStream_t stream)
{
  const float* img1 = (const float*)d_in[0];
  const float* img2 = (const float*)d_in[1];
  const float* kern = (const float*)d_in[2];
  float* out = (float*)d_out;
  float* partial = (float*)d_ws;   // NBLK floats = 3 KiB

  ssim_strip_kernel<<<NBLK, BLOCK, 0, stream>>>(img1, img2, kern, partial);
  ssim_reduce_kernel<<<1, 256, 0, stream>>>(partial, out);
}